// Round 3
// baseline (151.622 us; speedup 1.0000x reference)
//
#include <hip/hip_runtime.h>
#include <hip/hip_bf16.h>

// CausalGraphDiscovery on MI355X. f32 buffers holding bf16-rounded values.
// Round 9: attack the mech-block CRITICAL PATH (not aggregate work).
//   r2 diagnosis: kernel = tail of mech blocks (~47us each); occupancy 9.4%
//   vs 30% full-grid => pair blocks done in ~6us, mech blocks ARE the kernel.
//   Cause: the preceding 256MiB poison-fill dirties all of L2/L3, so each of
//   the ~28 SERIAL dependent load-groups in the graph chain pays ~1.5-2k cyc.
//   Fix: float4-row weight loads (each thread: 4 outputs x K-slice) =>
//   layer1 2 groups (was 16), layer2 1 (was 8), layer3 1 (was 8), K-split
//   partials reduced via LDS scratch overlaid on dead avT. Phase B: 128 mech
//   blocks (1024 samples, 8 passes) + 1-ahead X prefetch. Pair: 1-ahead
//   prefetch. launch_bounds(512,4) pins VGPR<=128 => 2 blocks/CU.
//
// Grid: 368 blocks x 512 threads, all co-resident.
//   bid   0..127: mech block (v = bid>>3, chunk = bid&7 -> 1024 samples)
//   bid 128..367: pair MLP block p = bid-128
//   bid 0 additionally writes adj + scores diagonal.
//
// d_out (f32): [0,256) adj | [256,131328) predictions | [131328,131584) scores

typedef __attribute__((ext_vector_type(8))) short bf16x8;
typedef __attribute__((ext_vector_type(4))) short bf16x4;
typedef __attribute__((ext_vector_type(4))) float f32x4;

#define DEV __device__ __forceinline__
DEV short f2bf(float f){ __hip_bfloat16 h = __float2bfloat16(f); short s; __builtin_memcpy(&s,&h,2); return s; }

// ---- LDS union ----
// avT stride 532: multiple of 4 (16B float4 rows); 532 % 32 == 20 -> cov
// reads ~2-way conflicts (free). avT region is reused as red2[] K-split
// reduction scratch once cov is done (layers 1-3).
struct GraphSm {
    float avT[16 * 532];   // av transposed: avT[v][s]; later red2 scratch
    float part[512];
    float cov[256];
    float corr[256];
    float h1[256];
    float h2[128];
    float adj[256];
    float m[16];
    float stdv[16];
};                          // 40832 B
struct MechSm {
    short W2T[64 * 136];    // Wm2^T bf16, padded row 136       17408 B
    short H1[8][16 * 136];  // per-wave h1 staging              34816 B
    float W1[16 * 128];     // layer-1 weights, mask+self folded 8192 B
    float B1[128];
    float B2[64];
    float W3[64];
};                          // 61440 B
struct PairSm {
    float w0[32], w1[32], bb[32], w2[32];
    float red[512];
    float b2s;
};
union SmU { GraphSm g; MechSm m; PairSm p; };

__global__ void __launch_bounds__(512, 4) k_fused(
    const float* __restrict__ data,
    const float* __restrict__ Ws1, const float* __restrict__ bs1,
    const float* __restrict__ Ws2, const float* __restrict__ bs2,
    const float* __restrict__ Ws3, const float* __restrict__ bs3,
    const float* __restrict__ Wm1, const float* __restrict__ bm1,
    const float* __restrict__ Wm2, const float* __restrict__ bm2,
    const float* __restrict__ Wm3, const float* __restrict__ bm3,
    const float* __restrict__ Wt1, const float* __restrict__ bt1,
    const float* __restrict__ Wt2, const float* __restrict__ bt2,
    float* __restrict__ out)
{
    __shared__ __align__(16) SmU sm;
    __shared__ float pm_s[16];   // outside the union: survives phase flip
    __shared__ float hp_s;
    int tid = threadIdx.x, bid = blockIdx.x;

    if (bid >= 128) {
        // ================= pair MLP block (p = bid-128) =================
        int p = bid - 128;
        int i = p / 15, jr = p % 15;
        int j = jr + (jr >= i ? 1 : 0);
        if (tid < 32) {
            sm.p.w0[tid] = Wt1[p*64 + tid];
            sm.p.w1[tid] = Wt1[p*64 + 32 + tid];
            sm.p.bb[tid] = bt1[p*32 + tid];
            sm.p.w2[tid] = Wt2[p*32 + tid];
        }
        if (tid == 0) sm.p.b2s = bt2[p];
        __syncthreads();
        float b2sv = sm.p.b2s;
        float acc = 0.f;
        float nxa = data[tid*16 + i];      // 1-ahead prefetch pipeline
        float nxb = data[tid*16 + j];
        for (int it = 0; it < 16; ++it) {
            float xa = nxa, xb = nxb;
            if (it < 15) {
                int sn = (it+1)*512 + tid;
                nxa = data[sn*16 + i];
                nxb = data[sn*16 + j];
            }
            float za = 0.f, zb = 0.f;      // 2-way ILP split of serial chain
            #pragma unroll
            for (int h = 0; h < 32; h += 2) {
                float t1 = fmaf(xa, sm.p.w0[h],   fmaf(xb, sm.p.w1[h],   sm.p.bb[h]));
                za = fmaf(fmaxf(t1, 0.f), sm.p.w2[h],   za);
                float t2 = fmaf(xa, sm.p.w0[h+1], fmaf(xb, sm.p.w1[h+1], sm.p.bb[h+1]));
                zb = fmaf(fmaxf(t2, 0.f), sm.p.w2[h+1], zb);
            }
            float z = b2sv + za + zb;
            acc += __builtin_amdgcn_rcpf(1.f + __expf(-z));
        }
        sm.p.red[tid] = acc;
        __syncthreads();
        for (int off = 256; off > 0; off >>= 1) {
            if (tid < off) sm.p.red[tid] += sm.p.red[tid + off];
            __syncthreads();
        }
        if (tid == 0) out[256 + 131072 + i*16 + j] = sm.p.red[0] * (1.f/8192.f);
        return;
    }

    // ==================== mech block (v, chunk) =========================
    int v = bid >> 3, chunk = bid & 7;
    int gs0 = chunk * 1024;                // 1024 samples per block

    // ---------- phase A: redundant graph chain (all f32) -----------------
    {   // A1: av[v][s] = mean over 16 batches; coalesced float4 loads
        int vb = (tid & 3) * 4, sg = tid >> 2;     // sg in 0..127
        for (int k = 0; k < 4; ++k) {
            int s = sg + k*128;
            float ax=0.f, ay=0.f, az=0.f, aw=0.f;
            #pragma unroll
            for (int b = 0; b < 16; ++b) {
                float4 d4 = *(const float4*)&data[b*8192 + s*16 + vb];
                ax += d4.x; ay += d4.y; az += d4.z; aw += d4.w;
            }
            sm.g.avT[(vb+0)*532 + s] = ax * 0.0625f;
            sm.g.avT[(vb+1)*532 + s] = ay * 0.0625f;
            sm.g.avT[(vb+2)*532 + s] = az * 0.0625f;
            sm.g.avT[(vb+3)*532 + s] = aw * 0.0625f;
        }
    }
    __syncthreads();
    // A2: per-variable mean over SEQ
    if (tid < 128) {
        int vv = tid >> 3, sgm = tid & 7;
        const float* rp = &sm.g.avT[vv*532 + sgm*64];
        float a0=0.f, a1=0.f, a2=0.f, a3=0.f;
        for (int s = 0; s < 64; s += 4) {
            float4 fa = *(const float4*)&rp[s];
            a0 += fa.x; a1 += fa.y; a2 += fa.z; a3 += fa.w;
        }
        sm.g.part[tid] = (a0+a1)+(a2+a3);
    }
    __syncthreads();
    if (tid < 16) {
        float ms = 0.f;
        #pragma unroll
        for (int q = 0; q < 8; ++q) ms += sm.g.part[tid*8 + q];
        sm.g.m[tid] = ms * (1.f/512.f);
    }
    __syncthreads();
    {   // A3: cov partials, s-range split in 2 across thread halves
        int t = tid & 255, hh = tid >> 8;
        int ci = t >> 4, cj = t & 15;
        const float* pi_ = &sm.g.avT[ci*532 + hh*256];
        const float* pj_ = &sm.g.avT[cj*532 + hh*256];
        float a0=0.f, a1=0.f, a2=0.f, a3=0.f;
        #pragma unroll 8
        for (int s = 0; s < 256; s += 4) {
            float4 fa = *(const float4*)&pi_[s];
            float4 fb = *(const float4*)&pj_[s];
            a0 = fmaf(fa.x, fb.x, a0); a1 = fmaf(fa.y, fb.y, a1);
            a2 = fmaf(fa.z, fb.z, a2); a3 = fmaf(fa.w, fb.w, a3);
        }
        sm.g.part[tid] = (a0+a1)+(a2+a3);
    }
    __syncthreads();
    if (tid < 256) {
        int ci = tid >> 4, cj = tid & 15;
        sm.g.cov[tid] = sm.g.part[tid] + sm.g.part[256 + tid]
                      - 512.f * sm.g.m[ci] * sm.g.m[cj];
    }
    __syncthreads();
    if (tid < 16) sm.g.stdv[tid] = sqrtf(fmaxf(sm.g.cov[tid*17], 0.f));
    __syncthreads();
    if (tid < 256) {
        int ci = tid >> 4, cj = tid & 15;
        float den = sm.g.stdv[ci] * sm.g.stdv[cj];
        sm.g.corr[tid] = (den > 0.f && ci != cj) ? fabsf(sm.g.cov[tid]/den) : 0.f;
    }
    __syncthreads();

    float* red2 = sm.g.avT;     // avT dead after cov: reuse as K-split scratch

    {   // layer1: 256 outs; thread = (output-quad o4, K-split ks of 32)
        // float4 row loads -> 32 loads/thread in 2 vmcnt groups (was 16)
        int o4 = tid & 63, ks = tid >> 6;          // o4 0..63, ks 0..7
        const float* W1p = Ws1 + ks*32*256 + o4*4;
        const float* cp  = sm.g.corr + ks*32;
        float ax=0.f, ay=0.f, az=0.f, aw=0.f;
        float bx=0.f, by=0.f, bz=0.f, bw=0.f;
        #pragma unroll 8
        for (int i = 0; i < 32; i += 2) {
            float4 w0 = *(const float4*)&W1p[(i  )*256];
            float4 w1 = *(const float4*)&W1p[(i+1)*256];
            float c0 = cp[i], c1 = cp[i+1];
            ax=fmaf(c0,w0.x,ax); ay=fmaf(c0,w0.y,ay); az=fmaf(c0,w0.z,az); aw=fmaf(c0,w0.w,aw);
            bx=fmaf(c1,w1.x,bx); by=fmaf(c1,w1.y,by); bz=fmaf(c1,w1.z,bz); bw=fmaf(c1,w1.w,bw);
        }
        float4 r4; r4.x=ax+bx; r4.y=ay+by; r4.z=az+bz; r4.w=aw+bw;
        *(float4*)&red2[ks*256 + o4*4] = r4;
    }
    __syncthreads();
    if (tid < 256) {
        float s = bs1[tid];
        #pragma unroll
        for (int k2 = 0; k2 < 8; ++k2) s += red2[k2*256 + tid];
        sm.g.h1[tid] = fmaxf(s, 0.f);
    }
    __syncthreads();
    {   // layer2: 128 outs; 16 K-splits of 16 -> 16 loads/thread, 1 group
        int o4 = tid & 31, ks = tid >> 5;          // o4 0..31, ks 0..15
        const float* W2p = Ws2 + ks*16*128 + o4*4;
        const float* cp  = sm.g.h1 + ks*16;
        float ax=0.f, ay=0.f, az=0.f, aw=0.f;
        float bx=0.f, by=0.f, bz=0.f, bw=0.f;
        #pragma unroll
        for (int i = 0; i < 16; i += 2) {
            float4 w0 = *(const float4*)&W2p[(i  )*128];
            float4 w1 = *(const float4*)&W2p[(i+1)*128];
            float c0 = cp[i], c1 = cp[i+1];
            ax=fmaf(c0,w0.x,ax); ay=fmaf(c0,w0.y,ay); az=fmaf(c0,w0.z,az); aw=fmaf(c0,w0.w,aw);
            bx=fmaf(c1,w1.x,bx); by=fmaf(c1,w1.y,by); bz=fmaf(c1,w1.z,bz); bw=fmaf(c1,w1.w,bw);
        }
        float4 r4; r4.x=ax+bx; r4.y=ay+by; r4.z=az+bz; r4.w=aw+bw;
        *(float4*)&red2[ks*128 + o4*4] = r4;
    }
    __syncthreads();
    if (tid < 128) {
        float s = bs2[tid];
        #pragma unroll
        for (int k2 = 0; k2 < 16; ++k2) s += red2[k2*128 + tid];
        sm.g.h2[tid] = fmaxf(s, 0.f);
    }
    __syncthreads();
    {   // layer3: 256 outs; 8 K-splits of 16 -> 16 loads/thread, 1 group
        int o4 = tid & 63, ks = tid >> 6;          // o4 0..63, ks 0..7
        const float* W3p = Ws3 + ks*16*256 + o4*4;
        const float* cp  = sm.g.h2 + ks*16;
        float ax=0.f, ay=0.f, az=0.f, aw=0.f;
        float bx=0.f, by=0.f, bz=0.f, bw=0.f;
        #pragma unroll
        for (int i = 0; i < 16; i += 2) {
            float4 w0 = *(const float4*)&W3p[(i  )*256];
            float4 w1 = *(const float4*)&W3p[(i+1)*256];
            float c0 = cp[i], c1 = cp[i+1];
            ax=fmaf(c0,w0.x,ax); ay=fmaf(c0,w0.y,ay); az=fmaf(c0,w0.z,az); aw=fmaf(c0,w0.w,aw);
            bx=fmaf(c1,w1.x,bx); by=fmaf(c1,w1.y,by); bz=fmaf(c1,w1.z,bz); bw=fmaf(c1,w1.w,bw);
        }
        float4 r4; r4.x=ax+bx; r4.y=ay+by; r4.z=az+bz; r4.w=aw+bw;
        *(float4*)&red2[ks*256 + o4*4] = r4;
    }
    __syncthreads();
    if (tid < 256) {
        float z = bs3[tid];
        #pragma unroll
        for (int k2 = 0; k2 < 8; ++k2) z += red2[k2*256 + tid];
        float a = 1.f / (1.f + expf(-z));          // precise: feeds 0.5 threshold
        int r = tid >> 4, cc = tid & 15;
        float adjv = (r < cc) ? a : 0.f;           // triu(adj,1)
        sm.g.adj[tid] = adjv;
        if (bid == 0) out[tid] = adjv;             // one block owns adj write
    }
    __syncthreads();
    // pm/hp for OUR v (bit-identical across blocks: same ops, same data)
    if (tid < 15) {
        int jj = tid + (tid >= v ? 1 : 0);
        pm_s[tid] = (sm.g.adj[jj*16 + v] > 0.5f) ? 1.f : 0.f;
    }
    if (bid == 0 && tid >= 16 && tid < 32)
        out[256 + 131072 + (tid-16)*17] = 0.f;     // scores diagonal
    __syncthreads();
    if (tid == 0) {
        float s = 0.f;
        #pragma unroll
        for (int pr = 0; pr < 15; ++pr) s += pm_s[pr];
        hp_s = (s > 0.f) ? 1.f : 0.f;
    }
    __syncthreads();   // union flips: graph arrays dead from here

    // ---------- phase B: bf16-MFMA mech MLP (1024 samples) ---------------
    for (int e = tid; e < 2048; e += 512) {        // Wfull (mask+self folded)
        int k = e >> 7, h = e & 127;
        float val = 0.f;
        if (k != v) {
            int p = k - (k > v ? 1 : 0);
            val = Wm1[v*1920 + p*128 + h] * pm_s[p];
        }
        sm.m.W1[e] = val;
    }
    for (int e = tid; e < 8192; e += 512) {        // Wm2^T -> bf16
        int h = e >> 6, jj2 = e & 63;
        sm.m.W2T[jj2*136 + h] = f2bf(Wm2[v*8192 + e]);
    }
    if (tid < 128) sm.m.B1[tid] = bm1[v*128 + tid];
    else if (tid < 192) sm.m.B2[tid - 128] = bm2[v*64 + tid - 128];
    else if (tid < 256) sm.m.W3[tid - 192] = Wm3[v*64 + tid - 192];
    __syncthreads();

    int lane = tid & 63, wid = tid >> 6;           // wid 0..7
    int c = lane & 15, q = lane >> 4;
    float hp = hp_s;
    float bm3v = bm3[v];

    bf16x8 a1f[8];
    #pragma unroll
    for (int ht = 0; ht < 8; ++ht) {
        #pragma unroll
        for (int jj = 0; jj < 8; ++jj) {
            int k = q*8 + jj;
            float w = (k < 16) ? sm.m.W1[k*128 + ht*16 + c] : 0.f;
            a1f[ht][jj] = f2bf(w);
        }
    }
    bf16x8 b2r[16];
    #pragma unroll
    for (int jt = 0; jt < 4; ++jt)
        #pragma unroll
        for (int ks = 0; ks < 4; ++ks)
            b2r[jt*4 + ks] = *(const bf16x8*)&sm.m.W2T[(jt*16 + c)*136 + ks*32 + q*8];
    float w3c[4], b2c[4];
    #pragma unroll
    for (int jt = 0; jt < 4; ++jt) { w3c[jt] = sm.m.W3[jt*16 + c]; b2c[jt] = sm.m.B2[jt*16 + c]; }

    short* h1buf = sm.m.H1[wid];
    bool act = (q < 2);

    // 1-ahead software pipeline on the X-tile loads
    float4 u0c, u1c;
    {
        int st0 = wid*8;
        if (act) {
            const float* xp = &data[(gs0 + st0*16 + c)*16 + q*8];
            u0c = *(const float4*)xp;
            u1c = *(const float4*)(xp + 4);
        }
    }

    for (int stl = 0; stl < 8; ++stl) {
        int st = wid*8 + stl;                       // 0..63 (1024 samples)
        float4 u0 = u0c, u1 = u1c;
        if (stl < 7 && act) {                       // prefetch next pass
            const float* xp = &data[(gs0 + (st+1)*16 + c)*16 + q*8];
            u0c = *(const float4*)xp;
            u1c = *(const float4*)(xp + 4);
        }
        bf16x8 xb;
        #pragma unroll
        for (int i2 = 0; i2 < 8; ++i2) xb[i2] = 0;
        if (act) {
            xb[0] = f2bf(u0.x); xb[1] = f2bf(u0.y);
            xb[2] = f2bf(u0.z); xb[3] = f2bf(u0.w);
            xb[4] = f2bf(u1.x); xb[5] = f2bf(u1.y);
            xb[6] = f2bf(u1.z); xb[7] = f2bf(u1.w);
        }
        f32x4 c1[8];
        #pragma unroll
        for (int ht = 0; ht < 8; ++ht) c1[ht] = *(const f32x4*)&sm.m.B1[ht*16 + q*4];
        #pragma unroll
        for (int ht = 0; ht < 8; ++ht)
            c1[ht] = __builtin_amdgcn_mfma_f32_16x16x32_bf16(a1f[ht], xb, c1[ht], 0, 0, 0);
        #pragma unroll
        for (int ht = 0; ht < 8; ++ht) {
            bf16x4 pk;
            #pragma unroll
            for (int r = 0; r < 4; ++r) pk[r] = f2bf(fmaxf(c1[ht][r], 0.f));
            *(bf16x4*)&h1buf[c*136 + ht*16 + q*4] = pk;
        }
        f32x4 c2[4];
        #pragma unroll
        for (int jt = 0; jt < 4; ++jt) {
            float bi = b2c[jt];
            c2[jt] = (f32x4){bi, bi, bi, bi};
        }
        #pragma unroll
        for (int ks = 0; ks < 4; ++ks) {
            bf16x8 a2 = *(const bf16x8*)&h1buf[c*136 + ks*32 + q*8];
            #pragma unroll
            for (int jt = 0; jt < 4; ++jt)
                c2[jt] = __builtin_amdgcn_mfma_f32_16x16x32_bf16(a2, b2r[jt*4 + ks], c2[jt], 0, 0, 0);
        }
        float part[4];
        #pragma unroll
        for (int r = 0; r < 4; ++r) part[r] = 0.f;
        #pragma unroll
        for (int jt = 0; jt < 4; ++jt)
            #pragma unroll
            for (int r = 0; r < 4; ++r)
                part[r] = fmaf(fmaxf(c2[jt][r], 0.f), w3c[jt], part[r]);
        #pragma unroll
        for (int off = 1; off < 16; off <<= 1)
            #pragma unroll
            for (int r = 0; r < 4; ++r)
                part[r] += __shfl_xor(part[r], off, 16);
        if (c == 0) {
            #pragma unroll
            for (int r = 0; r < 4; ++r) {
                int s_loc = st*16 + q*4 + r;
                float mech = part[r] + bm3v;
                float xv = data[(gs0 + s_loc)*16 + v];   // f32 exact fallback
                out[256 + (gs0 + s_loc)*16 + v] = (hp != 0.f) ? mech : xv;
            }
        }
    }
}

// ---------------------------------------------------------------- launch
extern "C" void kernel_launch(void* const* d_in, const int* in_sizes, int n_in,
                              void* d_out, int out_size, void* d_ws, size_t ws_size,
                              hipStream_t stream)
{
    const float* data = (const float*)d_in[0];
    const float* Ws1  = (const float*)d_in[1];
    const float* bs1  = (const float*)d_in[2];
    const float* Ws2  = (const float*)d_in[3];
    const float* bs2  = (const float*)d_in[4];
    const float* Ws3  = (const float*)d_in[5];
    const float* bs3  = (const float*)d_in[6];
    const float* Wm1  = (const float*)d_in[7];
    const float* bm1  = (const float*)d_in[8];
    const float* Wm2  = (const float*)d_in[9];
    const float* bm2  = (const float*)d_in[10];
    const float* Wm3  = (const float*)d_in[11];
    const float* bm3  = (const float*)d_in[12];
    const float* Wt1  = (const float*)d_in[13];
    const float* bt1  = (const float*)d_in[14];
    const float* Wt2  = (const float*)d_in[15];
    const float* bt2  = (const float*)d_in[16];
    float* out = (float*)d_out;
    (void)d_ws; (void)ws_size; (void)in_sizes; (void)n_in; (void)out_size;

    hipLaunchKernelGGL(k_fused, dim3(368), dim3(512), 0, stream,
                       data, Ws1, bs1, Ws2, bs2, Ws3, bs3,
                       Wm1, bm1, Wm2, bm2, Wm3, bm3,
                       Wt1, bt1, Wt2, bt2, out);
}

// Round 4
// 117.721 us; speedup vs baseline: 1.2880x; 1.2880x over previous
//
#include <hip/hip_runtime.h>
#include <hip/hip_bf16.h>

// CausalGraphDiscovery on MI355X. f32 buffers holding bf16-rounded values.
// Round 10: REVERT the VGPR cap that poisoned round 9.
//   r9 post-mortem: __launch_bounds__(512,4) forced VGPR 88->64; phase-B MFMA
//   fragments (b2r[16] = 64 VGPRs) spilled to scratch -> WRITE_SIZE 1->28MB,
//   FETCH 6->20MB, k_fused 47->79us. The r9 critical-path restructure
//   (float4-row weight loads: layer1 16->2 serial load-groups, layer2 8->1,
//   layer3 8->1; K-split partials via LDS scratch) never got a clean test.
//   This round: identical to r9 but __launch_bounds__(512,2) (r2's proven
//   setting: 88 VGPR, no spill, 4 waves/SIMD natural, 2 blocks/CU by LDS).
//
// Grid: 368 blocks x 512 threads, all co-resident.
//   bid   0..127: mech block (v = bid>>3, chunk = bid&7 -> 1024 samples)
//   bid 128..367: pair MLP block p = bid-128
//   bid 0 additionally writes adj + scores diagonal.
//
// d_out (f32): [0,256) adj | [256,131328) predictions | [131328,131584) scores

typedef __attribute__((ext_vector_type(8))) short bf16x8;
typedef __attribute__((ext_vector_type(4))) short bf16x4;
typedef __attribute__((ext_vector_type(4))) float f32x4;

#define DEV __device__ __forceinline__
DEV short f2bf(float f){ __hip_bfloat16 h = __float2bfloat16(f); short s; __builtin_memcpy(&s,&h,2); return s; }

// ---- LDS union ----
// avT stride 532: multiple of 4 (16B float4 rows); 532 % 32 == 20 -> cov
// reads ~2-way conflicts (free). avT region is reused as red2[] K-split
// reduction scratch once cov is done (layers 1-3).
struct GraphSm {
    float avT[16 * 532];   // av transposed: avT[v][s]; later red2 scratch
    float part[512];
    float cov[256];
    float corr[256];
    float h1[256];
    float h2[128];
    float adj[256];
    float m[16];
    float stdv[16];
};                          // 40832 B
struct MechSm {
    short W2T[64 * 136];    // Wm2^T bf16, padded row 136       17408 B
    short H1[8][16 * 136];  // per-wave h1 staging              34816 B
    float W1[16 * 128];     // layer-1 weights, mask+self folded 8192 B
    float B1[128];
    float B2[64];
    float W3[64];
};                          // 61440 B
struct PairSm {
    float w0[32], w1[32], bb[32], w2[32];
    float red[512];
    float b2s;
};
union SmU { GraphSm g; MechSm m; PairSm p; };

__global__ void __launch_bounds__(512, 2) k_fused(
    const float* __restrict__ data,
    const float* __restrict__ Ws1, const float* __restrict__ bs1,
    const float* __restrict__ Ws2, const float* __restrict__ bs2,
    const float* __restrict__ Ws3, const float* __restrict__ bs3,
    const float* __restrict__ Wm1, const float* __restrict__ bm1,
    const float* __restrict__ Wm2, const float* __restrict__ bm2,
    const float* __restrict__ Wm3, const float* __restrict__ bm3,
    const float* __restrict__ Wt1, const float* __restrict__ bt1,
    const float* __restrict__ Wt2, const float* __restrict__ bt2,
    float* __restrict__ out)
{
    __shared__ __align__(16) SmU sm;
    __shared__ float pm_s[16];   // outside the union: survives phase flip
    __shared__ float hp_s;
    int tid = threadIdx.x, bid = blockIdx.x;

    if (bid >= 128) {
        // ================= pair MLP block (p = bid-128) =================
        int p = bid - 128;
        int i = p / 15, jr = p % 15;
        int j = jr + (jr >= i ? 1 : 0);
        if (tid < 32) {
            sm.p.w0[tid] = Wt1[p*64 + tid];
            sm.p.w1[tid] = Wt1[p*64 + 32 + tid];
            sm.p.bb[tid] = bt1[p*32 + tid];
            sm.p.w2[tid] = Wt2[p*32 + tid];
        }
        if (tid == 0) sm.p.b2s = bt2[p];
        __syncthreads();
        float b2sv = sm.p.b2s;
        float acc = 0.f;
        float nxa = data[tid*16 + i];      // 1-ahead prefetch pipeline
        float nxb = data[tid*16 + j];
        for (int it = 0; it < 16; ++it) {
            float xa = nxa, xb = nxb;
            if (it < 15) {
                int sn = (it+1)*512 + tid;
                nxa = data[sn*16 + i];
                nxb = data[sn*16 + j];
            }
            float za = 0.f, zb = 0.f;      // 2-way ILP split of serial chain
            #pragma unroll
            for (int h = 0; h < 32; h += 2) {
                float t1 = fmaf(xa, sm.p.w0[h],   fmaf(xb, sm.p.w1[h],   sm.p.bb[h]));
                za = fmaf(fmaxf(t1, 0.f), sm.p.w2[h],   za);
                float t2 = fmaf(xa, sm.p.w0[h+1], fmaf(xb, sm.p.w1[h+1], sm.p.bb[h+1]));
                zb = fmaf(fmaxf(t2, 0.f), sm.p.w2[h+1], zb);
            }
            float z = b2sv + za + zb;
            acc += __builtin_amdgcn_rcpf(1.f + __expf(-z));
        }
        sm.p.red[tid] = acc;
        __syncthreads();
        for (int off = 256; off > 0; off >>= 1) {
            if (tid < off) sm.p.red[tid] += sm.p.red[tid + off];
            __syncthreads();
        }
        if (tid == 0) out[256 + 131072 + i*16 + j] = sm.p.red[0] * (1.f/8192.f);
        return;
    }

    // ==================== mech block (v, chunk) =========================
    int v = bid >> 3, chunk = bid & 7;
    int gs0 = chunk * 1024;                // 1024 samples per block

    // ---------- phase A: redundant graph chain (all f32) -----------------
    {   // A1: av[v][s] = mean over 16 batches; coalesced float4 loads
        int vb = (tid & 3) * 4, sg = tid >> 2;     // sg in 0..127
        for (int k = 0; k < 4; ++k) {
            int s = sg + k*128;
            float ax=0.f, ay=0.f, az=0.f, aw=0.f;
            #pragma unroll
            for (int b = 0; b < 16; ++b) {
                float4 d4 = *(const float4*)&data[b*8192 + s*16 + vb];
                ax += d4.x; ay += d4.y; az += d4.z; aw += d4.w;
            }
            sm.g.avT[(vb+0)*532 + s] = ax * 0.0625f;
            sm.g.avT[(vb+1)*532 + s] = ay * 0.0625f;
            sm.g.avT[(vb+2)*532 + s] = az * 0.0625f;
            sm.g.avT[(vb+3)*532 + s] = aw * 0.0625f;
        }
    }
    __syncthreads();
    // A2: per-variable mean over SEQ
    if (tid < 128) {
        int vv = tid >> 3, sgm = tid & 7;
        const float* rp = &sm.g.avT[vv*532 + sgm*64];
        float a0=0.f, a1=0.f, a2=0.f, a3=0.f;
        for (int s = 0; s < 64; s += 4) {
            float4 fa = *(const float4*)&rp[s];
            a0 += fa.x; a1 += fa.y; a2 += fa.z; a3 += fa.w;
        }
        sm.g.part[tid] = (a0+a1)+(a2+a3);
    }
    __syncthreads();
    if (tid < 16) {
        float ms = 0.f;
        #pragma unroll
        for (int q = 0; q < 8; ++q) ms += sm.g.part[tid*8 + q];
        sm.g.m[tid] = ms * (1.f/512.f);
    }
    __syncthreads();
    {   // A3: cov partials, s-range split in 2 across thread halves
        int t = tid & 255, hh = tid >> 8;
        int ci = t >> 4, cj = t & 15;
        const float* pi_ = &sm.g.avT[ci*532 + hh*256];
        const float* pj_ = &sm.g.avT[cj*532 + hh*256];
        float a0=0.f, a1=0.f, a2=0.f, a3=0.f;
        #pragma unroll 8
        for (int s = 0; s < 256; s += 4) {
            float4 fa = *(const float4*)&pi_[s];
            float4 fb = *(const float4*)&pj_[s];
            a0 = fmaf(fa.x, fb.x, a0); a1 = fmaf(fa.y, fb.y, a1);
            a2 = fmaf(fa.z, fb.z, a2); a3 = fmaf(fa.w, fb.w, a3);
        }
        sm.g.part[tid] = (a0+a1)+(a2+a3);
    }
    __syncthreads();
    if (tid < 256) {
        int ci = tid >> 4, cj = tid & 15;
        sm.g.cov[tid] = sm.g.part[tid] + sm.g.part[256 + tid]
                      - 512.f * sm.g.m[ci] * sm.g.m[cj];
    }
    __syncthreads();
    if (tid < 16) sm.g.stdv[tid] = sqrtf(fmaxf(sm.g.cov[tid*17], 0.f));
    __syncthreads();
    if (tid < 256) {
        int ci = tid >> 4, cj = tid & 15;
        float den = sm.g.stdv[ci] * sm.g.stdv[cj];
        sm.g.corr[tid] = (den > 0.f && ci != cj) ? fabsf(sm.g.cov[tid]/den) : 0.f;
    }
    __syncthreads();

    float* red2 = sm.g.avT;     // avT dead after cov: reuse as K-split scratch

    {   // layer1: 256 outs; thread = (output-quad o4, K-split ks of 32)
        // float4 row loads -> 32 loads/thread in 2 vmcnt groups (was 16)
        int o4 = tid & 63, ks = tid >> 6;          // o4 0..63, ks 0..7
        const float* W1p = Ws1 + ks*32*256 + o4*4;
        const float* cp  = sm.g.corr + ks*32;
        float ax=0.f, ay=0.f, az=0.f, aw=0.f;
        float bx=0.f, by=0.f, bz=0.f, bw=0.f;
        #pragma unroll 8
        for (int i = 0; i < 32; i += 2) {
            float4 w0 = *(const float4*)&W1p[(i  )*256];
            float4 w1 = *(const float4*)&W1p[(i+1)*256];
            float c0 = cp[i], c1 = cp[i+1];
            ax=fmaf(c0,w0.x,ax); ay=fmaf(c0,w0.y,ay); az=fmaf(c0,w0.z,az); aw=fmaf(c0,w0.w,aw);
            bx=fmaf(c1,w1.x,bx); by=fmaf(c1,w1.y,by); bz=fmaf(c1,w1.z,bz); bw=fmaf(c1,w1.w,bw);
        }
        float4 r4; r4.x=ax+bx; r4.y=ay+by; r4.z=az+bz; r4.w=aw+bw;
        *(float4*)&red2[ks*256 + o4*4] = r4;
    }
    __syncthreads();
    if (tid < 256) {
        float s = bs1[tid];
        #pragma unroll
        for (int k2 = 0; k2 < 8; ++k2) s += red2[k2*256 + tid];
        sm.g.h1[tid] = fmaxf(s, 0.f);
    }
    __syncthreads();
    {   // layer2: 128 outs; 16 K-splits of 16 -> 16 loads/thread, 1 group
        int o4 = tid & 31, ks = tid >> 5;          // o4 0..31, ks 0..15
        const float* W2p = Ws2 + ks*16*128 + o4*4;
        const float* cp  = sm.g.h1 + ks*16;
        float ax=0.f, ay=0.f, az=0.f, aw=0.f;
        float bx=0.f, by=0.f, bz=0.f, bw=0.f;
        #pragma unroll
        for (int i = 0; i < 16; i += 2) {
            float4 w0 = *(const float4*)&W2p[(i  )*128];
            float4 w1 = *(const float4*)&W2p[(i+1)*128];
            float c0 = cp[i], c1 = cp[i+1];
            ax=fmaf(c0,w0.x,ax); ay=fmaf(c0,w0.y,ay); az=fmaf(c0,w0.z,az); aw=fmaf(c0,w0.w,aw);
            bx=fmaf(c1,w1.x,bx); by=fmaf(c1,w1.y,by); bz=fmaf(c1,w1.z,bz); bw=fmaf(c1,w1.w,bw);
        }
        float4 r4; r4.x=ax+bx; r4.y=ay+by; r4.z=az+bz; r4.w=aw+bw;
        *(float4*)&red2[ks*128 + o4*4] = r4;
    }
    __syncthreads();
    if (tid < 128) {
        float s = bs2[tid];
        #pragma unroll
        for (int k2 = 0; k2 < 16; ++k2) s += red2[k2*128 + tid];
        sm.g.h2[tid] = fmaxf(s, 0.f);
    }
    __syncthreads();
    {   // layer3: 256 outs; 8 K-splits of 16 -> 16 loads/thread, 1 group
        int o4 = tid & 63, ks = tid >> 6;          // o4 0..63, ks 0..7
        const float* W3p = Ws3 + ks*16*256 + o4*4;
        const float* cp  = sm.g.h2 + ks*16;
        float ax=0.f, ay=0.f, az=0.f, aw=0.f;
        float bx=0.f, by=0.f, bz=0.f, bw=0.f;
        #pragma unroll
        for (int i = 0; i < 16; i += 2) {
            float4 w0 = *(const float4*)&W3p[(i  )*256];
            float4 w1 = *(const float4*)&W3p[(i+1)*256];
            float c0 = cp[i], c1 = cp[i+1];
            ax=fmaf(c0,w0.x,ax); ay=fmaf(c0,w0.y,ay); az=fmaf(c0,w0.z,az); aw=fmaf(c0,w0.w,aw);
            bx=fmaf(c1,w1.x,bx); by=fmaf(c1,w1.y,by); bz=fmaf(c1,w1.z,bz); bw=fmaf(c1,w1.w,bw);
        }
        float4 r4; r4.x=ax+bx; r4.y=ay+by; r4.z=az+bz; r4.w=aw+bw;
        *(float4*)&red2[ks*256 + o4*4] = r4;
    }
    __syncthreads();
    if (tid < 256) {
        float z = bs3[tid];
        #pragma unroll
        for (int k2 = 0; k2 < 8; ++k2) z += red2[k2*256 + tid];
        float a = 1.f / (1.f + expf(-z));          // precise: feeds 0.5 threshold
        int r = tid >> 4, cc = tid & 15;
        float adjv = (r < cc) ? a : 0.f;           // triu(adj,1)
        sm.g.adj[tid] = adjv;
        if (bid == 0) out[tid] = adjv;             // one block owns adj write
    }
    __syncthreads();
    // pm/hp for OUR v (bit-identical across blocks: same ops, same data)
    if (tid < 15) {
        int jj = tid + (tid >= v ? 1 : 0);
        pm_s[tid] = (sm.g.adj[jj*16 + v] > 0.5f) ? 1.f : 0.f;
    }
    if (bid == 0 && tid >= 16 && tid < 32)
        out[256 + 131072 + (tid-16)*17] = 0.f;     // scores diagonal
    __syncthreads();
    if (tid == 0) {
        float s = 0.f;
        #pragma unroll
        for (int pr = 0; pr < 15; ++pr) s += pm_s[pr];
        hp_s = (s > 0.f) ? 1.f : 0.f;
    }
    __syncthreads();   // union flips: graph arrays dead from here

    // ---------- phase B: bf16-MFMA mech MLP (1024 samples) ---------------
    for (int e = tid; e < 2048; e += 512) {        // Wfull (mask+self folded)
        int k = e >> 7, h = e & 127;
        float val = 0.f;
        if (k != v) {
            int p = k - (k > v ? 1 : 0);
            val = Wm1[v*1920 + p*128 + h] * pm_s[p];
        }
        sm.m.W1[e] = val;
    }
    for (int e = tid; e < 8192; e += 512) {        // Wm2^T -> bf16
        int h = e >> 6, jj2 = e & 63;
        sm.m.W2T[jj2*136 + h] = f2bf(Wm2[v*8192 + e]);
    }
    if (tid < 128) sm.m.B1[tid] = bm1[v*128 + tid];
    else if (tid < 192) sm.m.B2[tid - 128] = bm2[v*64 + tid - 128];
    else if (tid < 256) sm.m.W3[tid - 192] = Wm3[v*64 + tid - 192];
    __syncthreads();

    int lane = tid & 63, wid = tid >> 6;           // wid 0..7
    int c = lane & 15, q = lane >> 4;
    float hp = hp_s;
    float bm3v = bm3[v];

    bf16x8 a1f[8];
    #pragma unroll
    for (int ht = 0; ht < 8; ++ht) {
        #pragma unroll
        for (int jj = 0; jj < 8; ++jj) {
            int k = q*8 + jj;
            float w = (k < 16) ? sm.m.W1[k*128 + ht*16 + c] : 0.f;
            a1f[ht][jj] = f2bf(w);
        }
    }
    bf16x8 b2r[16];
    #pragma unroll
    for (int jt = 0; jt < 4; ++jt)
        #pragma unroll
        for (int ks = 0; ks < 4; ++ks)
            b2r[jt*4 + ks] = *(const bf16x8*)&sm.m.W2T[(jt*16 + c)*136 + ks*32 + q*8];
    float w3c[4], b2c[4];
    #pragma unroll
    for (int jt = 0; jt < 4; ++jt) { w3c[jt] = sm.m.W3[jt*16 + c]; b2c[jt] = sm.m.B2[jt*16 + c]; }

    short* h1buf = sm.m.H1[wid];
    bool act = (q < 2);

    // 1-ahead software pipeline on the X-tile loads
    float4 u0c, u1c;
    {
        int st0 = wid*8;
        if (act) {
            const float* xp = &data[(gs0 + st0*16 + c)*16 + q*8];
            u0c = *(const float4*)xp;
            u1c = *(const float4*)(xp + 4);
        }
    }

    for (int stl = 0; stl < 8; ++stl) {
        int st = wid*8 + stl;                       // 0..63 (1024 samples)
        float4 u0 = u0c, u1 = u1c;
        if (stl < 7 && act) {                       // prefetch next pass
            const float* xp = &data[(gs0 + (st+1)*16 + c)*16 + q*8];
            u0c = *(const float4*)xp;
            u1c = *(const float4*)(xp + 4);
        }
        bf16x8 xb;
        #pragma unroll
        for (int i2 = 0; i2 < 8; ++i2) xb[i2] = 0;
        if (act) {
            xb[0] = f2bf(u0.x); xb[1] = f2bf(u0.y);
            xb[2] = f2bf(u0.z); xb[3] = f2bf(u0.w);
            xb[4] = f2bf(u1.x); xb[5] = f2bf(u1.y);
            xb[6] = f2bf(u1.z); xb[7] = f2bf(u1.w);
        }
        f32x4 c1[8];
        #pragma unroll
        for (int ht = 0; ht < 8; ++ht) c1[ht] = *(const f32x4*)&sm.m.B1[ht*16 + q*4];
        #pragma unroll
        for (int ht = 0; ht < 8; ++ht)
            c1[ht] = __builtin_amdgcn_mfma_f32_16x16x32_bf16(a1f[ht], xb, c1[ht], 0, 0, 0);
        #pragma unroll
        for (int ht = 0; ht < 8; ++ht) {
            bf16x4 pk;
            #pragma unroll
            for (int r = 0; r < 4; ++r) pk[r] = f2bf(fmaxf(c1[ht][r], 0.f));
            *(bf16x4*)&h1buf[c*136 + ht*16 + q*4] = pk;
        }
        f32x4 c2[4];
        #pragma unroll
        for (int jt = 0; jt < 4; ++jt) {
            float bi = b2c[jt];
            c2[jt] = (f32x4){bi, bi, bi, bi};
        }
        #pragma unroll
        for (int ks = 0; ks < 4; ++ks) {
            bf16x8 a2 = *(const bf16x8*)&h1buf[c*136 + ks*32 + q*8];
            #pragma unroll
            for (int jt = 0; jt < 4; ++jt)
                c2[jt] = __builtin_amdgcn_mfma_f32_16x16x32_bf16(a2, b2r[jt*4 + ks], c2[jt], 0, 0, 0);
        }
        float part[4];
        #pragma unroll
        for (int r = 0; r < 4; ++r) part[r] = 0.f;
        #pragma unroll
        for (int jt = 0; jt < 4; ++jt)
            #pragma unroll
            for (int r = 0; r < 4; ++r)
                part[r] = fmaf(fmaxf(c2[jt][r], 0.f), w3c[jt], part[r]);
        #pragma unroll
        for (int off = 1; off < 16; off <<= 1)
            #pragma unroll
            for (int r = 0; r < 4; ++r)
                part[r] += __shfl_xor(part[r], off, 16);
        if (c == 0) {
            #pragma unroll
            for (int r = 0; r < 4; ++r) {
                int s_loc = st*16 + q*4 + r;
                float mech = part[r] + bm3v;
                float xv = data[(gs0 + s_loc)*16 + v];   // f32 exact fallback
                out[256 + (gs0 + s_loc)*16 + v] = (hp != 0.f) ? mech : xv;
            }
        }
    }
}

// ---------------------------------------------------------------- launch
extern "C" void kernel_launch(void* const* d_in, const int* in_sizes, int n_in,
                              void* d_out, int out_size, void* d_ws, size_t ws_size,
                              hipStream_t stream)
{
    const float* data = (const float*)d_in[0];
    const float* Ws1  = (const float*)d_in[1];
    const float* bs1  = (const float*)d_in[2];
    const float* Ws2  = (const float*)d_in[3];
    const float* bs2  = (const float*)d_in[4];
    const float* Ws3  = (const float*)d_in[5];
    const float* bs3  = (const float*)d_in[6];
    const float* Wm1  = (const float*)d_in[7];
    const float* bm1  = (const float*)d_in[8];
    const float* Wm2  = (const float*)d_in[9];
    const float* bm2  = (const float*)d_in[10];
    const float* Wm3  = (const float*)d_in[11];
    const float* bm3  = (const float*)d_in[12];
    const float* Wt1  = (const float*)d_in[13];
    const float* bt1  = (const float*)d_in[14];
    const float* Wt2  = (const float*)d_in[15];
    const float* bt2  = (const float*)d_in[16];
    float* out = (float*)d_out;
    (void)d_ws; (void)ws_size; (void)in_sizes; (void)n_in; (void)out_size;

    hipLaunchKernelGGL(k_fused, dim3(368), dim3(512), 0, stream,
                       data, Ws1, bs1, Ws2, bs2, Ws3, bs3,
                       Wm1, bm1, Wm2, bm2, Wm3, bm3,
                       Wt1, bt1, Wt2, bt2, out);
}

// Round 5
// 115.538 us; speedup vs baseline: 1.3123x; 1.0189x over previous
//
#include <hip/hip_runtime.h>
#include <hip/hip_bf16.h>

// CausalGraphDiscovery on MI355X. f32 buffers holding bf16-rounded values.
// Round 11: collapse the mech-block stage chain + hide phase-B staging.
//   r4 status: kernel ~40us (below the 40us poison fills in top-5); fixed
//   harness overhead ~76us/iter. Mech block = ~17 barrier stages, mostly
//   1 block/CU -> each stage pays its latency serially.
//   This round:
//   - t=0 register prefetch of ALL phase-B weights (Wm1/Wm2/bm1/bm2/Wm3/bm3)
//     and graph biases (bs1/bs2/bs3): staging becomes LDS-only, hidden
//     under phase A. (+~27 VGPR, 88->~115 < 128, still 4 waves/SIMD.)
//   - stage merges: m folded into cov-partials (regs); cov[]+std stage gone
//     (per-thread redundant diag cov -> corr directly); pm_s/hp_s gone
//     (pm from adj inline during W1 staging; hp per-thread register).
//     ~17 -> ~11 barriers; only A1/L1/L2/L3 global-latency stages remain.
//
// Grid: 368 blocks x 512 threads.
//   bid   0..127: mech block (v = bid>>3, chunk = bid&7 -> 1024 samples)
//   bid 128..367: pair MLP block p = bid-128
//   bid 0 additionally writes adj + scores diagonal.
//
// d_out (f32): [0,256) adj | [256,131328) predictions | [131328,131584) scores

typedef __attribute__((ext_vector_type(8))) short bf16x8;
typedef __attribute__((ext_vector_type(4))) short bf16x4;
typedef __attribute__((ext_vector_type(4))) float f32x4;

#define DEV __device__ __forceinline__
DEV short f2bf(float f){ __hip_bfloat16 h = __float2bfloat16(f); short s; __builtin_memcpy(&s,&h,2); return s; }

// ---- LDS union ----
// avT stride 532: multiple of 4 (16B float4 rows); 532 % 32 == 20 -> cov
// reads ~2-way conflicts (free). avT reused as red2[] K-split scratch.
struct GraphSm {
    float avT[16 * 532];   // av transposed: avT[v][s]; later red2 scratch
    float part[512];       // cov partials
    float corr[256];
    float h1[256];
    float h2[128];         // A2 per-var partials, later layer-2 output
    float adj[256];
};                          // 39680 B
struct MechSm {
    short W2T[64 * 136];    // Wm2^T bf16, padded row 136       17408 B
    short H1[8][16 * 136];  // per-wave h1 staging              34816 B
    float W1[16 * 128];     // layer-1 weights, mask+self folded 8192 B
    float B1[128];
    float B2[64];
    float W3[64];
};                          // 61440 B
struct PairSm {
    float w0[32], w1[32], bb[32], w2[32];
    float red[512];
    float b2s;
};
union SmU { GraphSm g; MechSm m; PairSm p; };

__global__ void __launch_bounds__(512, 2) k_fused(
    const float* __restrict__ data,
    const float* __restrict__ Ws1, const float* __restrict__ bs1,
    const float* __restrict__ Ws2, const float* __restrict__ bs2,
    const float* __restrict__ Ws3, const float* __restrict__ bs3,
    const float* __restrict__ Wm1, const float* __restrict__ bm1,
    const float* __restrict__ Wm2, const float* __restrict__ bm2,
    const float* __restrict__ Wm3, const float* __restrict__ bm3,
    const float* __restrict__ Wt1, const float* __restrict__ bt1,
    const float* __restrict__ Wt2, const float* __restrict__ bt2,
    float* __restrict__ out)
{
    __shared__ __align__(16) SmU sm;
    int tid = threadIdx.x, bid = blockIdx.x;

    if (bid >= 128) {
        // ================= pair MLP block (p = bid-128) =================
        int p = bid - 128;
        int i = p / 15, jr = p % 15;
        int j = jr + (jr >= i ? 1 : 0);
        if (tid < 32) {
            sm.p.w0[tid] = Wt1[p*64 + tid];
            sm.p.w1[tid] = Wt1[p*64 + 32 + tid];
            sm.p.bb[tid] = bt1[p*32 + tid];
            sm.p.w2[tid] = Wt2[p*32 + tid];
        }
        if (tid == 0) sm.p.b2s = bt2[p];
        __syncthreads();
        float b2sv = sm.p.b2s;
        float acc = 0.f;
        float nxa = data[tid*16 + i];      // 1-ahead prefetch pipeline
        float nxb = data[tid*16 + j];
        for (int it = 0; it < 16; ++it) {
            float xa = nxa, xb = nxb;
            if (it < 15) {
                int sn = (it+1)*512 + tid;
                nxa = data[sn*16 + i];
                nxb = data[sn*16 + j];
            }
            float za = 0.f, zb = 0.f;      // 2-way ILP split of serial chain
            #pragma unroll
            for (int h = 0; h < 32; h += 2) {
                float t1 = fmaf(xa, sm.p.w0[h],   fmaf(xb, sm.p.w1[h],   sm.p.bb[h]));
                za = fmaf(fmaxf(t1, 0.f), sm.p.w2[h],   za);
                float t2 = fmaf(xa, sm.p.w0[h+1], fmaf(xb, sm.p.w1[h+1], sm.p.bb[h+1]));
                zb = fmaf(fmaxf(t2, 0.f), sm.p.w2[h+1], zb);
            }
            float z = b2sv + za + zb;
            acc += __builtin_amdgcn_rcpf(1.f + __expf(-z));
        }
        sm.p.red[tid] = acc;
        __syncthreads();
        for (int off = 256; off > 0; off >>= 1) {
            if (tid < off) sm.p.red[tid] += sm.p.red[tid + off];
            __syncthreads();
        }
        if (tid == 0) out[256 + 131072 + i*16 + j] = sm.p.red[0] * (1.f/8192.f);
        return;
    }

    // ==================== mech block (v, chunk) =========================
    int v = bid >> 3, chunk = bid & 7;
    int gs0 = chunk * 1024;                // 1024 samples per block

    // ---- t=0 prefetch: phase-B weights + graph biases (no dependencies) --
    float pf_wm1[4];
    {
        #pragma unroll
        for (int r = 0; r < 4; ++r) {
            int e = tid + 512*r;           // e < 2048
            int k = e >> 7, h = e & 127;
            pf_wm1[r] = 0.f;
            if (k != v) {
                int p = k - (k > v ? 1 : 0);
                pf_wm1[r] = Wm1[v*1920 + p*128 + h];
            }
        }
    }
    float4 pf_wm2[4];
    {
        const float* wp = Wm2 + v*8192 + tid*16;
        #pragma unroll
        for (int m4 = 0; m4 < 4; ++m4) pf_wm2[m4] = *(const float4*)&wp[m4*4];
    }
    float b1r  = bm1[v*128 + (tid & 127)];
    float b2r_ = bm2[v*64  + (tid & 63)];
    float w3r  = Wm3[v*64  + (tid & 63)];
    float bm3v = bm3[v];
    float bs1r = bs1[tid & 255];
    float bs2r = bs2[tid & 127];
    float bs3r = bs3[tid & 255];

    // ---------- phase A: redundant graph chain (all f32) -----------------
    {   // S1: av[v][s] = mean over 16 batches; coalesced float4 loads
        int vb = (tid & 3) * 4, sg = tid >> 2;     // sg in 0..127
        for (int k = 0; k < 4; ++k) {
            int s = sg + k*128;
            float ax=0.f, ay=0.f, az=0.f, aw=0.f;
            #pragma unroll
            for (int b = 0; b < 16; ++b) {
                float4 d4 = *(const float4*)&data[b*8192 + s*16 + vb];
                ax += d4.x; ay += d4.y; az += d4.z; aw += d4.w;
            }
            sm.g.avT[(vb+0)*532 + s] = ax * 0.0625f;
            sm.g.avT[(vb+1)*532 + s] = ay * 0.0625f;
            sm.g.avT[(vb+2)*532 + s] = az * 0.0625f;
            sm.g.avT[(vb+3)*532 + s] = aw * 0.0625f;
        }
    }
    __syncthreads();
    // S2: per-variable partial sums over SEQ -> h2[128] (scratch)
    if (tid < 128) {
        int vv = tid >> 3, sgm = tid & 7;
        const float* rp = &sm.g.avT[vv*532 + sgm*64];
        float a0=0.f, a1=0.f, a2=0.f, a3=0.f;
        for (int s = 0; s < 64; s += 4) {
            float4 fa = *(const float4*)&rp[s];
            a0 += fa.x; a1 += fa.y; a2 += fa.z; a3 += fa.w;
        }
        sm.g.h2[tid] = (a0+a1)+(a2+a3);
    }
    __syncthreads();
    // S3: cov partials (s-range split in 2) + per-thread means into regs
    int ci, cj; float mci, mcj;
    {
        int t = tid & 255, hh = tid >> 8;
        ci = t >> 4; cj = t & 15;
        mci = 0.f; mcj = 0.f;
        #pragma unroll
        for (int q = 0; q < 8; ++q) { mci += sm.g.h2[ci*8 + q]; mcj += sm.g.h2[cj*8 + q]; }
        mci *= (1.f/512.f); mcj *= (1.f/512.f);
        const float* pi_ = &sm.g.avT[ci*532 + hh*256];
        const float* pj_ = &sm.g.avT[cj*532 + hh*256];
        float a0=0.f, a1=0.f, a2=0.f, a3=0.f;
        #pragma unroll 8
        for (int s = 0; s < 256; s += 4) {
            float4 fa = *(const float4*)&pi_[s];
            float4 fb = *(const float4*)&pj_[s];
            a0 = fmaf(fa.x, fb.x, a0); a1 = fmaf(fa.y, fb.y, a1);
            a2 = fmaf(fa.z, fb.z, a2); a3 = fmaf(fa.w, fb.w, a3);
        }
        sm.g.part[tid] = (a0+a1)+(a2+a3);
    }
    __syncthreads();
    // S4: corr directly (per-thread redundant diag cov; no cov[]/std stage)
    if (tid < 256) {
        float cij = sm.g.part[tid] + sm.g.part[256 + tid] - 512.f*mci*mcj;
        float cii = sm.g.part[ci*17] + sm.g.part[256 + ci*17] - 512.f*mci*mci;
        float cjj = sm.g.part[cj*17] + sm.g.part[256 + cj*17] - 512.f*mcj*mcj;
        float den = sqrtf(fmaxf(cii, 0.f)) * sqrtf(fmaxf(cjj, 0.f));
        sm.g.corr[tid] = (den > 0.f && ci != cj) ? fabsf(cij/den) : 0.f;
    }
    __syncthreads();

    float* red2 = sm.g.avT;     // avT dead after S3: reuse as K-split scratch

    {   // S5 layer1: 256 outs; thread = (output-quad o4, K-split ks of 32)
        int o4 = tid & 63, ks = tid >> 6;          // o4 0..63, ks 0..7
        const float* W1p = Ws1 + ks*32*256 + o4*4;
        const float* cp  = sm.g.corr + ks*32;
        float ax=0.f, ay=0.f, az=0.f, aw=0.f;
        float bx=0.f, by=0.f, bz=0.f, bw=0.f;
        #pragma unroll 8
        for (int i = 0; i < 32; i += 2) {
            float4 w0 = *(const float4*)&W1p[(i  )*256];
            float4 w1 = *(const float4*)&W1p[(i+1)*256];
            float c0 = cp[i], c1 = cp[i+1];
            ax=fmaf(c0,w0.x,ax); ay=fmaf(c0,w0.y,ay); az=fmaf(c0,w0.z,az); aw=fmaf(c0,w0.w,aw);
            bx=fmaf(c1,w1.x,bx); by=fmaf(c1,w1.y,by); bz=fmaf(c1,w1.z,bz); bw=fmaf(c1,w1.w,bw);
        }
        float4 r4; r4.x=ax+bx; r4.y=ay+by; r4.z=az+bz; r4.w=aw+bw;
        *(float4*)&red2[ks*256 + o4*4] = r4;
    }
    __syncthreads();
    // S6: h1 reduce (+prefetched bs1)
    if (tid < 256) {
        float s = bs1r;
        #pragma unroll
        for (int k2 = 0; k2 < 8; ++k2) s += red2[k2*256 + tid];
        sm.g.h1[tid] = fmaxf(s, 0.f);
    }
    __syncthreads();
    {   // S7 layer2: 128 outs; 16 K-splits of 16
        int o4 = tid & 31, ks = tid >> 5;          // o4 0..31, ks 0..15
        const float* W2p = Ws2 + ks*16*128 + o4*4;
        const float* cp  = sm.g.h1 + ks*16;
        float ax=0.f, ay=0.f, az=0.f, aw=0.f;
        float bx=0.f, by=0.f, bz=0.f, bw=0.f;
        #pragma unroll
        for (int i = 0; i < 16; i += 2) {
            float4 w0 = *(const float4*)&W2p[(i  )*128];
            float4 w1 = *(const float4*)&W2p[(i+1)*128];
            float c0 = cp[i], c1 = cp[i+1];
            ax=fmaf(c0,w0.x,ax); ay=fmaf(c0,w0.y,ay); az=fmaf(c0,w0.z,az); aw=fmaf(c0,w0.w,aw);
            bx=fmaf(c1,w1.x,bx); by=fmaf(c1,w1.y,by); bz=fmaf(c1,w1.z,bz); bw=fmaf(c1,w1.w,bw);
        }
        float4 r4; r4.x=ax+bx; r4.y=ay+by; r4.z=az+bz; r4.w=aw+bw;
        *(float4*)&red2[ks*128 + o4*4] = r4;
    }
    __syncthreads();
    // S8: h2 reduce (+prefetched bs2)
    if (tid < 128) {
        float s = bs2r;
        #pragma unroll
        for (int k2 = 0; k2 < 16; ++k2) s += red2[k2*128 + tid];
        sm.g.h2[tid] = fmaxf(s, 0.f);
    }
    __syncthreads();
    {   // S9 layer3: 256 outs; 8 K-splits of 16
        int o4 = tid & 63, ks = tid >> 6;          // o4 0..63, ks 0..7
        const float* W3p = Ws3 + ks*16*256 + o4*4;
        const float* cp  = sm.g.h2 + ks*16;
        float ax=0.f, ay=0.f, az=0.f, aw=0.f;
        float bx=0.f, by=0.f, bz=0.f, bw=0.f;
        #pragma unroll
        for (int i = 0; i < 16; i += 2) {
            float4 w0 = *(const float4*)&W3p[(i  )*256];
            float4 w1 = *(const float4*)&W3p[(i+1)*256];
            float c0 = cp[i], c1 = cp[i+1];
            ax=fmaf(c0,w0.x,ax); ay=fmaf(c0,w0.y,ay); az=fmaf(c0,w0.z,az); aw=fmaf(c0,w0.w,aw);
            bx=fmaf(c1,w1.x,bx); by=fmaf(c1,w1.y,by); bz=fmaf(c1,w1.z,bz); bw=fmaf(c1,w1.w,bw);
        }
        float4 r4; r4.x=ax+bx; r4.y=ay+by; r4.z=az+bz; r4.w=aw+bw;
        *(float4*)&red2[ks*256 + o4*4] = r4;
    }
    __syncthreads();
    // S10: adj (+prefetched bs3)
    if (tid < 256) {
        float z = bs3r;
        #pragma unroll
        for (int k2 = 0; k2 < 8; ++k2) z += red2[k2*256 + tid];
        float a = 1.f / (1.f + expf(-z));          // precise: feeds 0.5 threshold
        int r = tid >> 4, cc = tid & 15;
        float adjv = (r < cc) ? a : 0.f;           // triu(adj,1)
        sm.g.adj[tid] = adjv;
        if (bid == 0) out[tid] = adjv;             // one block owns adj write
    }
    if (bid == 0 && tid >= 256 && tid < 272)
        out[256 + 131072 + (tid-256)*17] = 0.f;    // scores diagonal
    __syncthreads();

    // S11: phase-B LDS staging PURELY from prefetched registers + adj reads.
    //   pm inline: parent-slot p of variable k maps back to jj == k, so
    //   mask = adj[k*16+v] > 0.5.  hp computed per-thread into a register.
    #pragma unroll
    for (int r = 0; r < 4; ++r) {
        int e = tid + 512*r;
        int k = e >> 7;
        float val = 0.f;
        if (k != v && sm.g.adj[k*16 + v] > 0.5f) val = pf_wm1[r];
        sm.m.W1[e] = val;
    }
    float hp = 0.f;
    #pragma unroll
    for (int k = 0; k < 16; ++k)
        if (k != v && sm.g.adj[k*16 + v] > 0.5f) hp = 1.f;
    #pragma unroll
    for (int m4 = 0; m4 < 4; ++m4) {
        float4 w4 = pf_wm2[m4];
        int e0 = tid*16 + m4*4;
        int h = e0 >> 6;                            // same for all 4 elems
        int jj0 = e0 & 63;
        sm.m.W2T[(jj0+0)*136 + h] = f2bf(w4.x);
        sm.m.W2T[(jj0+1)*136 + h] = f2bf(w4.y);
        sm.m.W2T[(jj0+2)*136 + h] = f2bf(w4.z);
        sm.m.W2T[(jj0+3)*136 + h] = f2bf(w4.w);
    }
    if (tid < 128) sm.m.B1[tid] = b1r;
    else if (tid < 192) sm.m.B2[tid - 128] = b2r_;
    else if (tid < 256) sm.m.W3[tid - 192] = w3r;
    __syncthreads();

    // ---------- phase B: bf16-MFMA mech MLP (1024 samples) ---------------
    int lane = tid & 63, wid = tid >> 6;           // wid 0..7
    int c = lane & 15, q = lane >> 4;

    bf16x8 a1f[8];
    #pragma unroll
    for (int ht = 0; ht < 8; ++ht) {
        #pragma unroll
        for (int jj = 0; jj < 8; ++jj) {
            int k = q*8 + jj;
            float w = (k < 16) ? sm.m.W1[k*128 + ht*16 + c] : 0.f;
            a1f[ht][jj] = f2bf(w);
        }
    }
    bf16x8 b2r[16];
    #pragma unroll
    for (int jt = 0; jt < 4; ++jt)
        #pragma unroll
        for (int ks = 0; ks < 4; ++ks)
            b2r[jt*4 + ks] = *(const bf16x8*)&sm.m.W2T[(jt*16 + c)*136 + ks*32 + q*8];
    float w3c[4], b2c[4];
    #pragma unroll
    for (int jt = 0; jt < 4; ++jt) { w3c[jt] = sm.m.W3[jt*16 + c]; b2c[jt] = sm.m.B2[jt*16 + c]; }

    short* h1buf = sm.m.H1[wid];
    bool act = (q < 2);

    // 1-ahead software pipeline on the X-tile loads
    float4 u0c, u1c;
    {
        int st0 = wid*8;
        if (act) {
            const float* xp = &data[(gs0 + st0*16 + c)*16 + q*8];
            u0c = *(const float4*)xp;
            u1c = *(const float4*)(xp + 4);
        }
    }

    for (int stl = 0; stl < 8; ++stl) {
        int st = wid*8 + stl;                       // 0..63 (1024 samples)
        float4 u0 = u0c, u1 = u1c;
        if (stl < 7 && act) {                       // prefetch next pass
            const float* xp = &data[(gs0 + (st+1)*16 + c)*16 + q*8];
            u0c = *(const float4*)xp;
            u1c = *(const float4*)(xp + 4);
        }
        bf16x8 xb;
        #pragma unroll
        for (int i2 = 0; i2 < 8; ++i2) xb[i2] = 0;
        if (act) {
            xb[0] = f2bf(u0.x); xb[1] = f2bf(u0.y);
            xb[2] = f2bf(u0.z); xb[3] = f2bf(u0.w);
            xb[4] = f2bf(u1.x); xb[5] = f2bf(u1.y);
            xb[6] = f2bf(u1.z); xb[7] = f2bf(u1.w);
        }
        f32x4 c1[8];
        #pragma unroll
        for (int ht = 0; ht < 8; ++ht) c1[ht] = *(const f32x4*)&sm.m.B1[ht*16 + q*4];
        #pragma unroll
        for (int ht = 0; ht < 8; ++ht)
            c1[ht] = __builtin_amdgcn_mfma_f32_16x16x32_bf16(a1f[ht], xb, c1[ht], 0, 0, 0);
        #pragma unroll
        for (int ht = 0; ht < 8; ++ht) {
            bf16x4 pk;
            #pragma unroll
            for (int r = 0; r < 4; ++r) pk[r] = f2bf(fmaxf(c1[ht][r], 0.f));
            *(bf16x4*)&h1buf[c*136 + ht*16 + q*4] = pk;
        }
        f32x4 c2[4];
        #pragma unroll
        for (int jt = 0; jt < 4; ++jt) {
            float bi = b2c[jt];
            c2[jt] = (f32x4){bi, bi, bi, bi};
        }
        #pragma unroll
        for (int ks = 0; ks < 4; ++ks) {
            bf16x8 a2 = *(const bf16x8*)&h1buf[c*136 + ks*32 + q*8];
            #pragma unroll
            for (int jt = 0; jt < 4; ++jt)
                c2[jt] = __builtin_amdgcn_mfma_f32_16x16x32_bf16(a2, b2r[jt*4 + ks], c2[jt], 0, 0, 0);
        }
        float part[4];
        #pragma unroll
        for (int r = 0; r < 4; ++r) part[r] = 0.f;
        #pragma unroll
        for (int jt = 0; jt < 4; ++jt)
            #pragma unroll
            for (int r = 0; r < 4; ++r)
                part[r] = fmaf(fmaxf(c2[jt][r], 0.f), w3c[jt], part[r]);
        #pragma unroll
        for (int off = 1; off < 16; off <<= 1)
            #pragma unroll
            for (int r = 0; r < 4; ++r)
                part[r] += __shfl_xor(part[r], off, 16);
        if (c == 0) {
            #pragma unroll
            for (int r = 0; r < 4; ++r) {
                int s_loc = st*16 + q*4 + r;
                float mech = part[r] + bm3v;
                float xv = data[(gs0 + s_loc)*16 + v];   // f32 exact fallback
                out[256 + (gs0 + s_loc)*16 + v] = (hp != 0.f) ? mech : xv;
            }
        }
    }
}

// ---------------------------------------------------------------- launch
extern "C" void kernel_launch(void* const* d_in, const int* in_sizes, int n_in,
                              void* d_out, int out_size, void* d_ws, size_t ws_size,
                              hipStream_t stream)
{
    const float* data = (const float*)d_in[0];
    const float* Ws1  = (const float*)d_in[1];
    const float* bs1  = (const float*)d_in[2];
    const float* Ws2  = (const float*)d_in[3];
    const float* bs2  = (const float*)d_in[4];
    const float* Ws3  = (const float*)d_in[5];
    const float* bs3  = (const float*)d_in[6];
    const float* Wm1  = (const float*)d_in[7];
    const float* bm1  = (const float*)d_in[8];
    const float* Wm2  = (const float*)d_in[9];
    const float* bm2  = (const float*)d_in[10];
    const float* Wm3  = (const float*)d_in[11];
    const float* bm3  = (const float*)d_in[12];
    const float* Wt1  = (const float*)d_in[13];
    const float* bt1  = (const float*)d_in[14];
    const float* Wt2  = (const float*)d_in[15];
    const float* bt2  = (const float*)d_in[16];
    float* out = (float*)d_out;
    (void)d_ws; (void)ws_size; (void)in_sizes; (void)n_in; (void)out_size;

    hipLaunchKernelGGL(k_fused, dim3(368), dim3(512), 0, stream,
                       data, Ws1, bs1, Ws2, bs2, Ws3, bs3,
                       Wm1, bm1, Wm2, bm2, Wm3, bm3,
                       Wt1, bt1, Wt2, bt2, out);
}